// Round 1
// baseline (253.875 us; speedup 1.0000x reference)
//
#include <hip/hip_runtime.h>

typedef _Float16 half8 __attribute__((ext_vector_type(8)));
typedef _Float16 half4v __attribute__((ext_vector_type(4)));
typedef float f32x4 __attribute__((ext_vector_type(4)));

#define KP 328                 // LDS row pitch (fp16 elems): 320 + 8 pad (bank stagger)
#define OFF_PRED 26214400      // 32*128*128*50
#define OFF_XU   56934400      // OFF_PRED + 32*64*300*50

// ---- K0: build stacked weight matrix M[576][320] fp16: rows 0..255 = C, 256..555 = A, rest 0
__global__ void build_M(const float* __restrict__ A, const float* __restrict__ C,
                        _Float16* __restrict__ M) {
    int idx = blockIdx.x * 256 + threadIdx.x;
    if (idx >= 576 * 320) return;
    int m = idx / 320, k = idx % 320;
    float v = 0.f;
    if (k < 300) {
        if (m < 256) v = C[m * 300 + k];
        else if (m < 556) v = A[(m - 256) * 300 + k];
    }
    M[idx] = (_Float16)v;
}

// ---- K1: per-(b,p) GEMM  Y[556][51] = M · [x0 | X_bp], fused scatter epilogue
__global__ __launch_bounds__(256) void gemm_main(
    const float* __restrict__ X, const float* __restrict__ x0,
    const _Float16* __restrict__ M, float* __restrict__ out)
{
    __shared__ _Float16 lds[64 * KP];   // [n=0..63][k], n0 = x0, n=t+1 = X[:,t]
    const int bp = blockIdx.x;
    const int b = bp >> 6, p = bp & 63;
    const int tid = threadIdx.x;
    const float* Xbp = X + bp * 15000;

    // zero the k in [300,328) pad for all 64 rows (MFMA k-loop covers k<320; M pad cols are 0,
    // but NaN-pattern garbage * 0 = NaN, so pad must be真 zero)
    if (tid < 64) {
        uint32_t* rowp = (uint32_t*)(lds + tid * KP + 300);
        #pragma unroll
        for (int k = 0; k < 14; k++) rowp[k] = 0u;
    }
    // x0 -> row n=0
    if (tid < 75) {
        const float* s = x0 + bp * 300 + tid * 4;
        half4v h = { (_Float16)s[0], (_Float16)s[1], (_Float16)s[2], (_Float16)s[3] };
        *(half4v*)(lds + tid * 4) = h;
    }
    // X (k-major [300][50]) -> LDS transposed rows n=t+1, 4 k's per ds_write_b64
    for (int i = tid; i < 3750; i += 256) {
        int t = i % 50, jq = i / 50;
        const float* s = Xbp + (jq * 4) * 50 + t;
        half4v h = { (_Float16)s[0], (_Float16)s[50], (_Float16)s[100], (_Float16)s[150] };
        *(half4v*)(lds + (t + 1) * KP + jq * 4) = h;
    }
    __syncthreads();

    const int wave = tid >> 6, lane = tid & 63;
    const int lr = lane & 15, lg = lane >> 4;

    f32x4 acc[9][4];                    // [m-tile within wave][n-tile]
    #pragma unroll
    for (int j = 0; j < 9; j++)
        #pragma unroll
        for (int nt = 0; nt < 4; nt++)
            acc[j][nt] = (f32x4){0.f, 0.f, 0.f, 0.f};

    // B-frag (M): lane holds col m = mt*16 + lr, k = ks*32 + lg*8 + e  (16B contiguous)
    const _Float16* Mw = M + (wave * 144 + lr) * 320 + lg * 8;
    // A-frag (X^T in LDS): lane holds row n = nt*16 + lr, same k slice
    const _Float16* Lb = lds + lr * KP + lg * 8;

    for (int ks = 0; ks < 10; ks++) {
        half8 a[4];
        #pragma unroll
        for (int nt = 0; nt < 4; nt++)
            a[nt] = *(const half8*)(Lb + nt * 16 * KP + ks * 32);
        #pragma unroll
        for (int j = 0; j < 9; j++) {
            half8 bf = *(const half8*)(Mw + j * 16 * 320 + ks * 32);
            #pragma unroll
            for (int nt = 0; nt < 4; nt++)
                acc[j][nt] = __builtin_amdgcn_mfma_f32_16x16x32_f16(a[nt], bf, acc[j][nt], 0, 0, 0);
        }
    }

    // epilogue: D tile (mt, nt): row n = nt*16 + lg*4 + q (ext-col index), col m = mt*16 + lr
    const int gr = p >> 3, gc = p & 7;
    #pragma unroll
    for (int j = 0; j < 9; j++) {
        int mt = wave * 9 + j;
        int colm = mt * 16 + lr;
        if (colm < 256) {
            // recon row d = colm: vid[b][gr*16+mt][gc*16+lr][t], t = n-1
            int base = b * 819200 + (((gr * 16 + mt) * 128) + gc * 16 + lr) * 50;
            #pragma unroll
            for (int nt = 0; nt < 4; nt++) {
                int t0 = nt * 16 + lg * 4;
                #pragma unroll
                for (int q = 0; q < 4; q++) {
                    int n = t0 + q;
                    if (n >= 1 && n < 51) out[base + n - 1] = acc[j][nt][q];
                }
            }
        } else if (colm < 556) {
            // X_pred row i = colm-256, t = n
            int base = OFF_PRED + (bp * 300 + (colm - 256)) * 50;
            #pragma unroll
            for (int nt = 0; nt < 4; nt++) {
                int t0 = nt * 16 + lg * 4;
                #pragma unroll
                for (int q = 0; q < 4; q++) {
                    int n = t0 + q;
                    if (n < 50) out[base + n] = acc[j][nt][q];
                }
            }
        }
    }
}

// ---- K2: X_U[b,i,t] = 0.5*(1+exp(-(B·U)[b,i,t])) * sum_p |X[b,p,i,t]|
__global__ void xu_kernel(const float* __restrict__ X, const float* __restrict__ U,
                          const float* __restrict__ B, float* __restrict__ out) {
    int id = blockIdx.x * 256 + threadIdx.x;
    if (id >= 480000) return;
    int t = id % 50;
    int i = (id / 50) % 300;
    int b = id / 15000;
    const float* xp = X + b * 960000 + i * 50 + t;
    float s = 0.f;
    #pragma unroll 8
    for (int pp = 0; pp < 64; pp++) s += fabsf(xp[pp * 15000]);
    float bu = 0.f;
    const float* up = U + b * 2000 + t;
    const float* Bp = B + i * 40;
    #pragma unroll 8
    for (int q = 0; q < 40; q++) bu += Bp[q] * up[q * 50];
    out[OFF_XU + id] = 0.5f * (1.f + expf(-bu)) * s;
}

extern "C" void kernel_launch(void* const* d_in, const int* in_sizes, int n_in,
                              void* d_out, int out_size, void* d_ws, size_t ws_size,
                              hipStream_t stream) {
    const float* X  = (const float*)d_in[0];
    const float* U  = (const float*)d_in[1];
    const float* x0 = (const float*)d_in[2];
    const float* A  = (const float*)d_in[3];
    const float* B  = (const float*)d_in[4];
    const float* C  = (const float*)d_in[5];
    float* out = (float*)d_out;
    _Float16* M = (_Float16*)d_ws;      // 576*320*2 = 368,640 B

    build_M<<<720, 256, 0, stream>>>(A, C, M);
    gemm_main<<<2048, 256, 0, stream>>>(X, x0, M, out);
    xu_kernel<<<1875, 256, 0, stream>>>(X, U, B, out);
}

// Round 2
// 211.086 us; speedup vs baseline: 1.2027x; 1.2027x over previous
//
#include <hip/hip_runtime.h>

typedef _Float16 half8 __attribute__((ext_vector_type(8)));
typedef _Float16 half4v __attribute__((ext_vector_type(4)));
typedef float f32x4 __attribute__((ext_vector_type(4)));

#define KP 328                 // LDS row pitch (fp16 elems): 320 + 8 pad
#define MROWS 640              // M padded rows: 0..255=C, 256..555=A, 556..639=0
#define OFF_PRED 26214400      // 32*128*128*50
#define OFF_XU   56934400      // OFF_PRED + 32*64*300*50

// ---- K0: build stacked weight matrix M[640][320] fp16
__global__ void build_M(const float* __restrict__ A, const float* __restrict__ C,
                        _Float16* __restrict__ M) {
    int idx = blockIdx.x * 256 + threadIdx.x;
    if (idx >= MROWS * 320) return;
    int m = idx / 320, k = idx % 320;
    float v = 0.f;
    if (k < 300) {
        if (m < 256) v = C[m * 300 + k];
        else if (m < 556) v = A[(m - 256) * 300 + k];
    }
    M[idx] = (_Float16)v;
}

// ---- K1: per-(b,p) GEMM  Y[640][64] = M · [x0 | X_bp], fused scatter epilogue
//      8 waves; wave w owns m-rows [80w, 80w+80) (5 m-tiles) x 4 n-tiles
__global__ __launch_bounds__(512) void gemm_main(
    const float* __restrict__ X, const float* __restrict__ x0,
    const _Float16* __restrict__ M, float* __restrict__ out)
{
    __shared__ _Float16 lds[64 * KP];   // [n=0..63][k], n0 = x0, n=t+1 = X[:,t]
    const int bp = blockIdx.x;
    const int b = bp >> 6, p = bp & 63;
    const int tid = threadIdx.x;
    const float* Xbp = X + bp * 15000;

    // zero the k in [300,328) pad for all 64 rows
    if (tid < 64) {
        uint32_t* rowp = (uint32_t*)(lds + tid * KP + 300);
        #pragma unroll
        for (int k = 0; k < 14; k++) rowp[k] = 0u;
    }
    // x0 -> row n=0
    if (tid < 75) {
        const float* s = x0 + bp * 300 + tid * 4;
        half4v h = { (_Float16)s[0], (_Float16)s[1], (_Float16)s[2], (_Float16)s[3] };
        *(half4v*)(lds + tid * 4) = h;
    }
    // X (k-major [300][50]) -> LDS transposed rows n=t+1
    for (int i = tid; i < 3750; i += 512) {
        int t = i % 50, jq = i / 50;
        const float* s = Xbp + (jq * 4) * 50 + t;
        half4v h = { (_Float16)s[0], (_Float16)s[50], (_Float16)s[100], (_Float16)s[150] };
        *(half4v*)(lds + (t + 1) * KP + jq * 4) = h;
    }
    __syncthreads();

    const int wave = tid >> 6, lane = tid & 63;
    const int lr = lane & 15, lg = lane >> 4;

    f32x4 acc[5][4];                    // [m-tile within wave][n-tile]
    #pragma unroll
    for (int j = 0; j < 5; j++)
        #pragma unroll
        for (int nt = 0; nt < 4; nt++)
            acc[j][nt] = (f32x4){0.f, 0.f, 0.f, 0.f};

    // B-frag (M): lane holds col m = wave*80 + j*16 + lr, k = ks*32 + lg*8 + e
    const _Float16* Mw = M + (wave * 80 + lr) * 320 + lg * 8;
    // A-frag (X^T in LDS): lane holds row n = nt*16 + lr, same k slice
    const _Float16* Lb = lds + lr * KP + lg * 8;

    for (int ks = 0; ks < 10; ks++) {
        half8 a[4];
        #pragma unroll
        for (int nt = 0; nt < 4; nt++)
            a[nt] = *(const half8*)(Lb + nt * 16 * KP + ks * 32);
        #pragma unroll
        for (int j = 0; j < 5; j++) {
            half8 bf = *(const half8*)(Mw + j * 16 * 320 + ks * 32);
            #pragma unroll
            for (int nt = 0; nt < 4; nt++)
                acc[j][nt] = __builtin_amdgcn_mfma_f32_16x16x32_f16(a[nt], bf, acc[j][nt], 0, 0, 0);
        }
    }

    // epilogue: D tile: row n = nt*16 + lg*4 + q (ext-col idx), col m = wave*80 + j*16 + lr
    const int gr = p >> 3, gc = p & 7;
    #pragma unroll
    for (int j = 0; j < 5; j++) {
        int colm = wave * 80 + j * 16 + lr;
        if (colm < 256) {
            // recon row d = colm -> vid[b][gr*16 + d/16][gc*16 + d%16][t], t = n-1
            int base = b * 819200 + ((gr * 16 + (colm >> 4)) * 128 + gc * 16 + (colm & 15)) * 50;
            #pragma unroll
            for (int nt = 0; nt < 4; nt++) {
                int t0 = nt * 16 + lg * 4;  // n start
                if (nt == 0 && lg == 0) {
                    out[base + 0] = acc[j][0][1];
                    out[base + 1] = acc[j][0][2];
                    out[base + 2] = acc[j][0][3];
                } else if (t0 <= 46) {
                    f32x4 v = acc[j][nt];
                    __builtin_memcpy(&out[base + t0 - 1], &v, 16);
                } else if (t0 == 48) {
                    out[base + 47] = acc[j][nt][0];
                    out[base + 48] = acc[j][nt][1];
                    out[base + 49] = acc[j][nt][2];
                }
            }
        } else if (colm < 556) {
            // X_pred row i = colm-256, t = n
            int base = OFF_PRED + (bp * 300 + (colm - 256)) * 50;
            #pragma unroll
            for (int nt = 0; nt < 4; nt++) {
                int t0 = nt * 16 + lg * 4;
                if (t0 <= 46) {
                    f32x4 v = acc[j][nt];
                    __builtin_memcpy(&out[base + t0], &v, 16);
                } else if (t0 == 48) {
                    out[base + 48] = acc[j][nt][0];
                    out[base + 49] = acc[j][nt][1];
                }
            }
        }
    }
}

// ---- K2: X_U[b,i,t] = 0.5*(1+exp(-(B·U)[b,i,t])) * sum_p |X[b,p,i,t]|
__global__ void xu_kernel(const float* __restrict__ X, const float* __restrict__ U,
                          const float* __restrict__ B, float* __restrict__ out) {
    int id = blockIdx.x * 256 + threadIdx.x;
    if (id >= 480000) return;
    int t = id % 50;
    int i = (id / 50) % 300;
    int b = id / 15000;
    const float* xp = X + b * 960000 + i * 50 + t;
    float s = 0.f;
    #pragma unroll 8
    for (int pp = 0; pp < 64; pp++) s += fabsf(xp[pp * 15000]);
    float bu = 0.f;
    const float* up = U + b * 2000 + t;
    const float* Bp = B + i * 40;
    #pragma unroll 8
    for (int q = 0; q < 40; q++) bu += Bp[q] * up[q * 50];
    out[OFF_XU + id] = 0.5f * (1.f + expf(-bu)) * s;
}

extern "C" void kernel_launch(void* const* d_in, const int* in_sizes, int n_in,
                              void* d_out, int out_size, void* d_ws, size_t ws_size,
                              hipStream_t stream) {
    const float* X  = (const float*)d_in[0];
    const float* U  = (const float*)d_in[1];
    const float* x0 = (const float*)d_in[2];
    const float* A  = (const float*)d_in[3];
    const float* B  = (const float*)d_in[4];
    const float* C  = (const float*)d_in[5];
    float* out = (float*)d_out;
    _Float16* M = (_Float16*)d_ws;      // 640*320*2 = 409,600 B

    build_M<<<800, 256, 0, stream>>>(A, C, M);
    gemm_main<<<2048, 512, 0, stream>>>(X, x0, M, out);
    xu_kernel<<<1875, 256, 0, stream>>>(X, U, B, out);
}